// Round 1
// baseline (468.962 us; speedup 1.0000x reference)
//
#include <hip/hip_runtime.h>

#define E_TOTAL 600000
#define NTILES (E_TOTAL / 64)  // 9375
#define NB 512                 // persistent blocks: 2 resident per CU x 256 CUs
#define LDH 264  // LDS row stride in shorts; 528 B -> balanced banks, 16B aligned

typedef __attribute__((ext_vector_type(8))) short short8;
typedef __attribute__((ext_vector_type(4))) float f32x4;

__device__ __forceinline__ unsigned f2bf_u(float f) {
  union { float f; unsigned u; } v; v.f = f;
  return (v.u + 0x7fffu + ((v.u >> 16) & 1u)) >> 16;  // RNE
}

// LDS-only barrier: drain ds ops, do NOT drain vmcnt (global loads stay in flight).
__device__ __forceinline__ void ldsBarrier() {
  asm volatile("s_waitcnt lgkmcnt(0)\n\ts_barrier" ::: "memory");
}

// ---- weight prep: tiled transpose+cast. W1[k][n]->W1t[n][k] bf16, W2 likewise ----
__global__ __launch_bounds__(256) void prep_weights(
    const float* __restrict__ W1, const float* __restrict__ W2,
    unsigned short* __restrict__ W1t, unsigned short* __restrict__ W2t) {
  __shared__ float t[32][33];
  int bid = blockIdx.x;
  const float* S; unsigned short* D; int k0, n0, N;
  if (bid < 64) { S = W1; D = W1t; N = 256; k0 = (bid >> 3) * 32; n0 = (bid & 7) * 32; }
  else { bid -= 64; S = W2; D = W2t; N = 64; k0 = (bid >> 1) * 32; n0 = (bid & 1) * 32; }
  int tx = threadIdx.x & 31, ty = threadIdx.x >> 5;
#pragma unroll
  for (int i = 0; i < 32; i += 8) t[ty + i][tx] = S[(k0 + ty + i) * N + n0 + tx];
  __syncthreads();
#pragma unroll
  for (int i = 0; i < 32; i += 8)
    D[(n0 + ty + i) * 256 + k0 + tx] = (unsigned short)f2bf_u(t[tx][ty + i]);
}

// ---- fused edge MLP: persistent blocks, cross-tile software pipeline ----
// Steady state per tile t:  gather(t+NB) issued at loop top, in flight across
// phase1(t)+phase2(t); idx(t+2NB) issued during hidden phase; feat(t+NB)
// converted+stored after bar4 (phase2 LDS reads done). vmcnt never drained
// by barriers, so ~3000 cycles of latency hiding per gather.
__global__ __launch_bounds__(256, 2) void edge_mlp(
    const float* __restrict__ x, const int* __restrict__ ei,
    const unsigned short* __restrict__ W1t, const unsigned short* __restrict__ W2t,
    const float* __restrict__ b1, const float* __restrict__ b2,
    float* __restrict__ out) {
  __shared__ __align__(16) unsigned short lds[64 * LDH];  // feat tile, reused as hidden
  __shared__ float ldsb1[256];
  __shared__ float ldsb2[64];

  const int tid = threadIdx.x;
  const int* __restrict__ srcI = ei;
  const int* __restrict__ dstI = ei + E_TOTAL;

  const int lane = tid & 63;
  const int w = tid >> 6;    // wave 0..3
  const int m = lane & 15;
  const int q = lane >> 4;

  const int kb = (tid & 31) * 8;        // 0..248, fixed per thread
  const int xo = kb & 127;
  const int e0 = tid >> 5;              // 0..7
  const int* __restrict__ idxp = (kb < 128) ? srcI : dstI;

  int w1off[4];
#pragma unroll
  for (int nt = 0; nt < 4; ++nt) w1off[nt] = ((w * 4 + nt) * 16 + m) * 256 + q * 8;
  const int w2off = (w * 16 + m) * 256 + q * 8;

  int t = blockIdx.x;

  // ---- prologue: idx(t) -> gather(t) -> idx(t+NB); biases; feat(t) -> LDS ----
  int nxt[8];
#pragma unroll
  for (int i = 0; i < 8; ++i) nxt[i] = idxp[t * 64 + e0 + 8 * i];

  float b2tmp = 0.f;
  if (tid < 64) b2tmp = b2[tid];
  float b1tmp = b1[tid];

  f32x4 g0[8], g1[8];
#pragma unroll
  for (int i = 0; i < 8; ++i) {
    const float* p = x + (size_t)((nxt[i] << 7) + xo);
    g0[i] = *(const f32x4*)p;
    g1[i] = *(const f32x4*)(p + 4);
  }

  if (t + NB < NTILES) {
#pragma unroll
    for (int i = 0; i < 8; ++i) nxt[i] = idxp[(t + NB) * 64 + e0 + 8 * i];
  }

  ldsb1[tid] = b1tmp;
  if (tid < 64) ldsb2[tid] = b2tmp;

#pragma unroll
  for (int i = 0; i < 8; ++i) {
    short8 s;
#pragma unroll
    for (int j = 0; j < 4; ++j) {
      s[j]     = (short)f2bf_u(g0[i][j]);
      s[4 + j] = (short)f2bf_u(g1[i][j]);
    }
    *(short8*)&lds[(e0 + 8 * i) * LDH + kb] = s;
  }

  short8 wa[2][4];
#pragma unroll
  for (int nt = 0; nt < 4; ++nt) wa[0][nt] = *(const short8*)&W1t[w1off[nt]];

  ldsBarrier();  // feat(t) visible

  for (; t < NTILES; t += NB) {
    const bool hn = (t + NB) < NTILES;

    // issue gather(t+NB): stays in flight through phase1+phase2
    if (hn) {
#pragma unroll
      for (int i = 0; i < 8; ++i) {
        const float* p = x + (size_t)((nxt[i] << 7) + xo);
        g0[i] = *(const f32x4*)p;
        g1[i] = *(const f32x4*)(p + 4);
      }
    }

    // ---- phase 1: D[n1][e] = sum_k W1t[n1][k] * feat[e][k] ----
    f32x4 acc[4][4];
#pragma unroll
    for (int nt = 0; nt < 4; ++nt)
#pragma unroll
      for (int mt = 0; mt < 4; ++mt) acc[nt][mt] = (f32x4){0.f, 0.f, 0.f, 0.f};

#pragma unroll
    for (int kk = 0; kk < 8; ++kk) {
      const int cur = kk & 1, nx = cur ^ 1;
      if (kk < 7) {
#pragma unroll
        for (int nt = 0; nt < 4; ++nt)
          wa[nx][nt] = *(const short8*)&W1t[w1off[nt] + (kk + 1) * 32];
      }
      short8 f[4];
#pragma unroll
      for (int mt = 0; mt < 4; ++mt)
        f[mt] = *(const short8*)&lds[(mt * 16 + m) * LDH + kk * 32 + q * 8];
#pragma unroll
      for (int nt = 0; nt < 4; ++nt)
#pragma unroll
        for (int mt = 0; mt < 4; ++mt)
          acc[nt][mt] = __builtin_amdgcn_mfma_f32_16x16x32_bf16(wa[cur][nt], f[mt], acc[nt][mt], 0, 0, 0);
    }

    ldsBarrier();  // bar2: feat reads done; safe to overwrite with hidden

    // ---- hidden phase: issue W2 frags, bias+relu+pack, issue idx(t+2NB) ----
    short8 w2f[8];
#pragma unroll
    for (int j = 0; j < 8; ++j) w2f[j] = *(const short8*)&W2t[w2off + j * 32];

    f32x4 bias[4];
#pragma unroll
    for (int nt = 0; nt < 4; ++nt) bias[nt] = *(const f32x4*)&ldsb1[w * 64 + nt * 16 + q * 4];
#pragma unroll
    for (int nt = 0; nt < 4; ++nt)
#pragma unroll
      for (int mt = 0; mt < 4; ++mt) {
        float h0 = fmaxf(acc[nt][mt][0] + bias[nt][0], 0.f);
        float h1 = fmaxf(acc[nt][mt][1] + bias[nt][1], 0.f);
        float h2 = fmaxf(acc[nt][mt][2] + bias[nt][2], 0.f);
        float h3 = fmaxf(acc[nt][mt][3] + bias[nt][3], 0.f);
        uint2 pk;
        pk.x = f2bf_u(h0) | (f2bf_u(h1) << 16);
        pk.y = f2bf_u(h2) | (f2bf_u(h3) << 16);
        *(uint2*)&lds[(mt * 16 + m) * LDH + w * 64 + nt * 16 + q * 4] = pk;
      }

    if (t + 2 * NB < NTILES) {
#pragma unroll
      for (int i = 0; i < 8; ++i) nxt[i] = idxp[(t + 2 * NB) * 64 + e0 + 8 * i];
    }

    ldsBarrier();  // bar3: hidden visible

    // ---- phase 2: D[n2][e] = sum_k W2t[n2][k] * hidden[e][k] ----
    f32x4 acc2[4];
#pragma unroll
    for (int mt = 0; mt < 4; ++mt) acc2[mt] = (f32x4){0.f, 0.f, 0.f, 0.f};
#pragma unroll
    for (int kk = 0; kk < 8; ++kk) {
#pragma unroll
      for (int mt = 0; mt < 4; ++mt) {
        short8 h = *(const short8*)&lds[(mt * 16 + m) * LDH + kk * 32 + q * 8];
        acc2[mt] = __builtin_amdgcn_mfma_f32_16x16x32_bf16(w2f[kk], h, acc2[mt], 0, 0, 0);
      }
    }

    f32x4 b2v = *(const f32x4*)&ldsb2[w * 16 + q * 4];
#pragma unroll
    for (int mt = 0; mt < 4; ++mt) {
      f32x4 o;
#pragma unroll
      for (int r = 0; r < 4; ++r) o[r] = acc2[mt][r] + b2v[r];
      *(f32x4*)&out[(t * 64 + mt * 16 + m) * 64 + w * 16 + q * 4] = o;
    }

    ldsBarrier();  // bar4: phase2 LDS reads done on all waves; feat region free

    // ---- convert + store feat(t+NB) (waits the in-flight gather), wa0 prefetch ----
    if (hn) {
#pragma unroll
      for (int i = 0; i < 8; ++i) {
        short8 s;
#pragma unroll
        for (int j = 0; j < 4; ++j) {
          s[j]     = (short)f2bf_u(g0[i][j]);
          s[4 + j] = (short)f2bf_u(g1[i][j]);
        }
        *(short8*)&lds[(e0 + 8 * i) * LDH + kb] = s;
      }
#pragma unroll
      for (int nt = 0; nt < 4; ++nt) wa[0][nt] = *(const short8*)&W1t[w1off[nt]];
    }
    ldsBarrier();  // bar1': feat(t+NB) visible for next iteration
  }
}

extern "C" void kernel_launch(void* const* d_in, const int* in_sizes, int n_in,
                              void* d_out, int out_size, void* d_ws, size_t ws_size,
                              hipStream_t stream) {
  const float* x  = (const float*)d_in[0];
  const int*   ei = (const int*)d_in[1];
  const float* W1 = (const float*)d_in[2];
  const float* b1 = (const float*)d_in[3];
  const float* W2 = (const float*)d_in[4];
  const float* b2 = (const float*)d_in[5];
  float* out = (float*)d_out;

  unsigned short* W1t = (unsigned short*)d_ws;   // 256*256 bf16
  unsigned short* W2t = W1t + 256 * 256;         // 64*256 bf16

  prep_weights<<<80, 256, 0, stream>>>(W1, W2, W1t, W2t);
  edge_mlp<<<NB, 256, 0, stream>>>(x, ei, W1t, W2t, b1, b2, out);
}